// Round 7
// baseline (432.660 us; speedup 1.0000x reference)
//
#include <hip/hip_runtime.h>
#include <hip/hip_bf16.h>
#include <stdint.h>

#define LQ 2048
#define LK 2048
#define DH 128
#define BQ 32          // q rows per workgroup
#define NT 8           // 8-way k-split: wave ks owns keys [ks*256, ks*256+256), 32/iter
#define LOG2E 1.44269504088896340736f
#define QSCALE 0.088388347648318447f   // 1/sqrt(128)

typedef __attribute__((ext_vector_type(8)))  short bf16x8;
typedef __attribute__((ext_vector_type(16))) float f32x16;
typedef __attribute__((ext_vector_type(4)))  float f32x4;

union FragAB { uint32_t u[4]; bf16x8 v; };

__device__ __forceinline__ uint32_t pack2_bf16(float lo, float hi) {
  union { __hip_bfloat16 b; uint16_t u; } a, c;
  a.b = __float2bfloat16(lo);
  c.b = __float2bfloat16(hi);
  return (uint32_t)a.u | ((uint32_t)c.u << 16);
}

// ============================================================================
// Pre-pass 1 (proven fast in R2): u -> keep-bit dwords, coalesced fattn layout
// maskb[(b*64+qb)*64 + kc][ln] : dword = keys [kc*32, kc*32+32) of row qb*32+ln
// ============================================================================
__global__ __launch_bounds__(256)
void mask_kernel(const float* __restrict__ uu, uint32_t* __restrict__ maskb) {
  const int lane = threadIdx.x & 63;
  const int wid  = blockIdx.x * 4 + (threadIdx.x >> 6);  // 8192 waves
#pragma unroll 1
  for (int i = 0; i < 16; ++i) {
    const size_t F = ((size_t)i * 8192 + wid) * 256;   // 256 consecutive floats
    float u0 = uu[F + 0 * 64 + lane];
    float u1 = uu[F + 1 * 64 + lane];
    float u2 = uu[F + 2 * 64 + lane];
    float u3 = uu[F + 3 * 64 + lane];
    unsigned long long B0 = __ballot(u0 >= 0.1f);
    unsigned long long B1 = __ballot(u1 >= 0.1f);
    unsigned long long B2 = __ballot(u2 >= 0.1f);
    unsigned long long B3 = __ballot(u3 >= 0.1f);
    if (lane < 8) {
      const int m = lane;
      unsigned long long bb = (m < 2) ? B0 : (m < 4) ? B1 : (m < 6) ? B2 : B3;
      uint32_t val = (m & 1) ? (uint32_t)(bb >> 32) : (uint32_t)bb;
      const int row = (int)(F >> 11);              // b*2048 + q
      const int c   = (int)((F >> 5) & 63) + m;    // 32-key group index
      const int bq  = row >> 5;                    // b*64 + (q>>5)
      const int ln  = row & 31;
      maskb[((size_t)bq * 64 + c) * 32 + ln] = val;
    }
  }
}

// ============================================================================
// Pre-pass 2: x2 f32 -> K_pre bf16 [b][key][d] and Vt_pre bf16 [b][d][key]
// ============================================================================
__global__ __launch_bounds__(256)
void prep_kernel(const float* __restrict__ x2, uint16_t* __restrict__ Kp,
                 uint16_t* __restrict__ Vp) {
  __shared__ uint16_t tl[128][130];
  const int b = blockIdx.x & 7, tile = blockIdx.x >> 3;
  const int t = threadIdx.x;
  const int row0 = t >> 1, half = t & 1;

  const float* src = x2 + ((size_t)(b * 2048 + tile * 128 + row0)) * 128 + half * 64;
  uint32_t wbuf[32];
#pragma unroll
  for (int i = 0; i < 16; ++i) {
    f32x4 v = *(const f32x4*)(src + i * 4);
    wbuf[2 * i]     = pack2_bf16(v.x, v.y);
    wbuf[2 * i + 1] = pack2_bf16(v.z, v.w);
  }
  uint16_t* kdst = Kp + ((size_t)(b * 2048 + tile * 128 + row0)) * 128 + half * 64;
#pragma unroll
  for (int i = 0; i < 8; ++i)
    *(uint4*)(kdst + i * 8) = *(const uint4*)&wbuf[i * 4];
#pragma unroll
  for (int i = 0; i < 32; ++i)
    *(uint32_t*)&tl[row0][half * 64 + 2 * i] = wbuf[i];
  __syncthreads();

  const int d = t >> 1, halfk = t & 1;
  uint32_t vw[32];
#pragma unroll
  for (int i = 0; i < 32; ++i) {
    const int k = halfk * 64 + 2 * i;
    vw[i] = (uint32_t)tl[k][d] | ((uint32_t)tl[k + 1][d] << 16);
  }
  uint16_t* vdst = Vp + ((size_t)(b * 128 + d)) * 2048 + tile * 128 + halfk * 64;
#pragma unroll
  for (int i = 0; i < 8; ++i)
    *(uint4*)(vdst + i * 8) = *(const uint4*)&vw[i * 4];
}

// ============================================================================
// Pre-pass 3: qm * LOG2E -> bf16 fragments, COALESCED per-wave layout:
// qmt3[((qb*64 + kc)*2 + h)*512 + ln*16 + gi]
// ============================================================================
__global__ __launch_bounds__(256)
void qmt_kernel(const float* __restrict__ qm, uint16_t* __restrict__ qmt3) {
  const int kc = threadIdx.x & 63;
  const int q  = blockIdx.x * 4 + (threadIdx.x >> 6);
  f32x4 r[8];
  const float* src = qm + (size_t)q * 2048 + kc * 32;
#pragma unroll
  for (int c = 0; c < 8; ++c) r[c] = *(const f32x4*)(src + c * 4);
#pragma unroll
  for (int h = 0; h < 2; ++h) {
    uint32_t w[8];
#pragma unroll
    for (int i = 0; i < 8; ++i) {
      const int gi0 = 2 * i, gi1 = 2 * i + 1;
      const float v0 = r[h + (gi0 >> 2) * 2][gi0 & 3] * LOG2E;
      const float v1 = r[h + (gi1 >> 2) * 2][gi1 & 3] * LOG2E;
      w[i] = pack2_bf16(v0, v1);
    }
    uint16_t* dst = qmt3 + (((size_t)(q >> 5) * 64 + kc) * 2 + h) * 512 + (q & 31) * 16;
    uint4 lo = {w[0], w[1], w[2], w[3]};
    uint4 hi = {w[4], w[5], w[6], w[7]};
    *(uint4*)dst = lo;
    *(uint4*)(dst + 8) = hi;
  }
}

// ============================================================================
// Main flash-attention kernel: 8 waves (8-way k-split, 256 keys each), grid
// 512, launch_bounds(512,4) -> 16 waves/CU (4/SIMD). No per-iter barriers,
// no LDS staging; K/V/mask/qm all coalesced or L2-local reads.
// ============================================================================
__global__ __launch_bounds__(512, 4)
void fattn_kernel(const float* __restrict__ x1,
                  const uint16_t* __restrict__ Kp,
                  const uint16_t* __restrict__ Vp,
                  const uint32_t* __restrict__ maskb,
                  const uint16_t* __restrict__ qmt3,
                  float* __restrict__ out)
{
  __shared__ float ml[2][8][64];       // 4 KB
  __shared__ f32x4 mscr[8][4][64];     // 32 KB (one acco quadrant per round)

  const int tid  = threadIdx.x;
  const int ks   = tid >> 6;           // wave = k-split index 0..7
  const int lane = tid & 63;
  const int ln   = lane & 31;
  const int h    = lane >> 5;

  const int b     = blockIdx.x & 7;    // batch -> XCD locality for Kp/Vp slice
  const int qblk  = blockIdx.x >> 3;   // 0..63
  const int qbase = qblk * BQ;
  const int qrow  = qbase + ln;        // this lane's q row

  // ---- Q fragments (B-operand of S^T mfma), scaled by QSCALE*LOG2E
  FragAB qf[8];
  {
    const float* qp = x1 + ((size_t)(b * LQ + qrow)) * DH + h * 8;
    const float qs = QSCALE * LOG2E;
#pragma unroll
    for (int dc = 0; dc < 8; ++dc) {
      f32x4 a = *(const f32x4*)(qp + dc * 16);
      f32x4 c = *(const f32x4*)(qp + dc * 16 + 4);
      qf[dc].u[0] = pack2_bf16(a.x * qs, a.y * qs);
      qf[dc].u[1] = pack2_bf16(a.z * qs, a.w * qs);
      qf[dc].u[2] = pack2_bf16(c.x * qs, c.y * qs);
      qf[dc].u[3] = pack2_bf16(c.z * qs, c.w * qs);
    }
  }

  const uint16_t* Kb = Kp + (size_t)(b * 2048 + ks * 256) * 128;  // [key][128d]
  const uint16_t* Vb = Vp + (size_t)b * 128 * 2048 + ks * 256;    // [d][2048k]
  const uint32_t* mb = maskb + ((size_t)(b * 64 + qblk) * 64 + ks * 8) * 32 + ln;
  const uint16_t* qmb = qmt3 + ((size_t)(qblk * 64 + ks * 8) * 2) * 512 + ln * 16;

  uint32_t M = mb[0];
  uint4 qc0, qc1;
  {
    const uint16_t* qp16 = qmb + h * 512;
    qc0 = *(const uint4*)qp16;
    qc1 = *(const uint4*)(qp16 + 8);
  }

  float m_run = -1e30f, l_run = 0.f;
  f32x16 acco[4];
#pragma unroll
  for (int d2 = 0; d2 < 4; ++d2)
#pragma unroll
    for (int i = 0; i < 16; ++i) acco[d2][i] = 0.f;

  for (int t = 0; t < NT; ++t) {
    // ---- this iter's K/V fragment loads (L2/L3 hits; 1 MB/batch slice)
    const uint16_t* Krow = Kb + (size_t)(t * 32 + ln) * 128 + h * 8;
    bf16x8 kf[8];
#pragma unroll
    for (int dc = 0; dc < 8; ++dc)
      kf[dc] = *(const bf16x8*)(Krow + dc * 16);

    bf16x8 vf[8];
#pragma unroll
    for (int d2 = 0; d2 < 4; ++d2)
#pragma unroll
      for (int c = 0; c < 2; ++c)
        vf[d2 * 2 + c] = *(const bf16x8*)(Vb + (size_t)(d2 * 32 + ln) * 2048 +
                                          t * 32 + c * 16 + h * 8);

    // ---- prefetch next iter's mask dword + qm fragments (coalesced)
    uint32_t Mn = 0; uint4 qn0, qn1;
    if (t + 1 < NT) {
      Mn = mb[(t + 1) * 32];
      const uint16_t* qp16 = qmb + ((size_t)(t + 1) * 2 + h) * 512;
      qn0 = *(const uint4*)qp16;
      qn1 = *(const uint4*)(qp16 + 8);
    }

    // ---- QK: S^T(32k x 32q) = K(32k x 16d) * Q^T(16d x 32q)
    f32x16 sacc;
#pragma unroll
    for (int i = 0; i < 16; ++i) sacc[i] = 0.f;
    __builtin_amdgcn_s_setprio(1);
#pragma unroll
    for (int dc = 0; dc < 8; ++dc)
      sacc = __builtin_amdgcn_mfma_f32_32x32x16_bf16(kf[dc], qf[dc].v, sacc, 0, 0, 0);
    __builtin_amdgcn_s_setprio(0);

    // ---- add qm*LOG2E (bf16 pre-packed in fragment order)
#define ADDQM(W, I) { sacc[I] += __uint_as_float((W) << 16); \
                      sacc[I + 1] += __uint_as_float((W) & 0xffff0000u); }
    ADDQM(qc0.x, 0)  ADDQM(qc0.y, 2)  ADDQM(qc0.z, 4)  ADDQM(qc0.w, 6)
    ADDQM(qc1.x, 8)  ADDQM(qc1.y, 10) ADDQM(qc1.z, 12) ADDQM(qc1.w, 14)
#undef ADDQM

    // ---- online softmax with defer-max (log2 domain; lane owns q-row)
    float pm = sacc[0];
#pragma unroll
    for (int i = 1; i < 16; ++i) pm = fmaxf(pm, sacc[i]);
    pm = fmaxf(pm, __shfl_xor(pm, 32));
    if (!__all(pm <= m_run + 8.f)) {
      const float mnew = fmaxf(m_run, pm);
      const float resc = __builtin_amdgcn_exp2f(m_run - mnew);
      l_run *= resc;
#pragma unroll
      for (int d2 = 0; d2 < 4; ++d2)
#pragma unroll
        for (int i = 0; i < 16; ++i) acco[d2][i] *= resc;
      m_run = mnew;
    }
    float rs = 0.f;
#pragma unroll
    for (int i = 0; i < 16; ++i) {
      sacc[i] = __builtin_amdgcn_exp2f(sacc[i] - m_run);
      rs += sacc[i];
    }
    rs += __shfl_xor(rs, 32);
    l_run += rs;                        // denominator WITHOUT dropout

    // ---- dropout on numerator (bit h*4 + g*8 + j2 of M)
#pragma unroll
    for (int g = 0; g < 4; ++g)
#pragma unroll
      for (int j2 = 0; j2 < 4; ++j2) {
        const uint32_t keep = (M >> (h * 4 + g * 8 + j2)) & 1u;
        sacc[g * 4 + j2] = keep ? sacc[g * 4 + j2] : 0.f;
      }

    // ---- pack bf16 pairs + exchange key-halves across lane-32 boundary
    uint32_t pr[4][2], sw[4][2];
#pragma unroll
    for (int g = 0; g < 4; ++g) {
      pr[g][0] = pack2_bf16(sacc[4 * g + 0], sacc[4 * g + 1]);
      pr[g][1] = pack2_bf16(sacc[4 * g + 2], sacc[4 * g + 3]);
      sw[g][0] = __shfl_xor(pr[g][0], 32);
      sw[g][1] = __shfl_xor(pr[g][1], 32);
    }
    FragAB bfr[2];
#pragma unroll
    for (int c = 0; c < 2; ++c) {
      bfr[c].u[0] = h ? sw[2 * c + 1][0] : pr[2 * c][0];
      bfr[c].u[1] = h ? sw[2 * c + 1][1] : pr[2 * c][1];
      bfr[c].u[2] = h ? pr[2 * c + 1][0] : sw[2 * c][0];
      bfr[c].u[3] = h ? pr[2 * c + 1][1] : sw[2 * c][1];
    }

    // ---- PV: out^T(32d x 32q) += V^T(32d x 16k) * P(16k x 32q)
    __builtin_amdgcn_s_setprio(1);
#pragma unroll
    for (int d2 = 0; d2 < 4; ++d2)
#pragma unroll
      for (int c = 0; c < 2; ++c)
        acco[d2] = __builtin_amdgcn_mfma_f32_32x32x16_bf16(vf[d2 * 2 + c], bfr[c].v,
                                                           acco[d2], 0, 0, 0);
    __builtin_amdgcn_s_setprio(0);

    if (t + 1 < NT) { M = Mn; qc0 = qn0; qc1 = qn1; }
  }

  // ---- 8-way k-split merge: 4 rounds (one acco quadrant at a time, 32KB LDS)
  ml[0][ks][lane] = m_run;
  ml[1][ks][lane] = l_run;

  float e[8], inv;
  float* op = out + ((size_t)(b * LQ + qbase + ln)) * DH;

#pragma unroll
  for (int r = 0; r < 4; ++r) {
    if (r) __syncthreads();             // previous round's reads done
#pragma unroll
    for (int g = 0; g < 4; ++g) {
      f32x4 vv;
#pragma unroll
      for (int j2 = 0; j2 < 4; ++j2) vv[j2] = acco[r][g * 4 + j2];
      mscr[ks][g][lane] = vv;
    }
    __syncthreads();                    // writes (and ml) visible

    if (r == 0) {
      float mM = -1e30f;
#pragma unroll
      for (int k = 0; k < 8; ++k) mM = fmaxf(mM, ml[0][k][lane]);
      float lM = 0.f;
#pragma unroll
      for (int k = 0; k < 8; ++k) {
        e[k] = __builtin_amdgcn_exp2f(ml[0][k][lane] - mM);
        lM += e[k] * ml[1][k][lane];
      }
      inv = (1.0f / 0.9f) / lM;         // fold dropout 1/(1-p)
    }

    if (ks < 4) {                       // wave ks handles g=ks for this quadrant
      f32x4 a4 = {0.f, 0.f, 0.f, 0.f};
#pragma unroll
      for (int k = 0; k < 8; ++k) a4 += e[k] * mscr[k][ks][lane];
      a4 = a4 * inv;
      *(f32x4*)(op + r * 32 + 8 * ks + 4 * h) = a4;
    }
  }
}

extern "C" void kernel_launch(void* const* d_in, const int* in_sizes, int n_in,
                              void* d_out, int out_size, void* d_ws, size_t ws_size,
                              hipStream_t stream) {
  (void)in_sizes; (void)n_in; (void)out_size; (void)ws_size;
  const float* x1 = (const float*)d_in[0];
  const float* x2 = (const float*)d_in[1];
  const float* qm = (const float*)d_in[2];
  const float* u  = (const float*)d_in[3];
  float* out = (float*)d_out;

  uint16_t* qmt3  = (uint16_t*)d_ws;                           // 8 MB
  uint16_t* Kp    = (uint16_t*)((char*)d_ws + (8u  << 20));    // 4 MB
  uint16_t* Vp    = (uint16_t*)((char*)d_ws + (12u << 20));    // 4 MB
  uint32_t* maskb = (uint32_t*)((char*)d_ws + (16u << 20));    // 4 MB

  mask_kernel<<<dim3(2048), dim3(256), 0, stream>>>(u, maskb);
  prep_kernel<<<dim3(128), dim3(256), 0, stream>>>(x2, Kp, Vp);
  qmt_kernel<<<dim3(512), dim3(256), 0, stream>>>(qm, qmt3);
  fattn_kernel<<<dim3(512), dim3(512), 0, stream>>>(x1, Kp, Vp, maskb, qmt3, out);
}